// Round 3
// baseline (522.714 us; speedup 1.0000x reference)
//
#include <hip/hip_runtime.h>
#include <hip/hip_bf16.h>
#include <math.h>

#define N_B 32
#define T_S 512
#define D_D 1024
#define C_C 120
#define SCALE 64.0f  // 2*sqrt(1024)

typedef unsigned short u16;
typedef __attribute__((ext_vector_type(8))) short short8;
typedef __attribute__((ext_vector_type(4))) float floatx4;

__device__ inline u16 f2bf(float f) {
    union { __hip_bfloat16 h; u16 u; } c; c.h = __float2bfloat16(f); return c.u;
}
__device__ inline float bf2f(u16 u) {
    union { unsigned i; float f; } c; c.i = ((unsigned)u) << 16; return c.f;
}

// async global->LDS, 16B per lane. LDS dest = wave-uniform base + lane*16.
__device__ inline void gll16(const void* g, void* l) {
    __builtin_amdgcn_global_load_lds((const __attribute__((address_space(1))) void*)g,
                                     (__attribute__((address_space(3))) void*)l,
                                     16, 0, 0);
}

// ---- mask dtype robustness: harness may deliver bool as int32 or int8 ----
__device__ inline bool mask_is_i8(const int* mk) {
    bool i8 = false;
#pragma unroll
    for (int i = 0; i < 16; i++) {
        unsigned v = ((const unsigned*)mk)[i];
        if (v > 1u) i8 = true;
    }
    return i8;
}
__device__ inline int mask_val(const int* mk, int idx, bool i8) {
    return i8 ? (int)((const signed char*)mk)[idx] : mk[idx];
}

// ==== k_prep: fused W_attn transpose (fp32) + W1 transpose (bf16) +
//      masked column-sum of x + valid count + x fp32->bf16 copy ====
// blocks [0,1024): transposes; blocks [1024,1792): xsum/copy
__global__ void k_prep(const float* __restrict__ W_attn, const float* __restrict__ W1,
                       const float* x0, const float* x1, const float* x2,
                       const int* m0, const int* m1, const int* m2,
                       float* __restrict__ WT, u16* __restrict__ W1T,
                       float* __restrict__ xsum, int* __restrict__ nvalid,
                       u16* __restrict__ xb) {
    int bx = blockIdx.x;
    int tid = threadIdx.x;
    if (bx < 1024) {
        int tbx = bx & 31, tby = bx >> 5;
        __shared__ float tile[32][33];
        int tx = tid & 31, ty = tid >> 5;  // ty 0..7
#pragma unroll
        for (int j = 0; j < 32; j += 8)
            tile[ty + j][tx] = W_attn[(size_t)(tby*32 + ty + j)*D_D + tbx*32 + tx];
        __syncthreads();
#pragma unroll
        for (int j = 0; j < 32; j += 8)
            WT[(size_t)(tbx*32 + ty + j)*D_D + tby*32 + tx] = tile[tx][ty + j];
        __syncthreads();
#pragma unroll
        for (int j = 0; j < 32; j += 8)
            tile[ty + j][tx] = W1[(size_t)(tby*32 + ty + j)*D_D + tbx*32 + tx];
        __syncthreads();
#pragma unroll
        for (int j = 0; j < 32; j += 8)
            W1T[(size_t)(tbx*32 + ty + j)*D_D + tby*32 + tx] = f2bf(tile[tx][ty + j]);
        return;
    }
    int idx = bx - 1024;
    int tc = idx & 7, b = (idx >> 3) & 31, z = idx >> 8;
    const float* x = z == 0 ? x0 : (z == 1 ? x1 : x2);
    const int* mk = z == 0 ? m0 : (z == 1 ? m1 : m2);
    bool i8 = mask_is_i8(mk);
    int t0 = tc * 64;
    const float4* xr = (const float4*)(x + (size_t)(b * T_S) * D_D);
    float4 acc = {0.f, 0.f, 0.f, 0.f};
#pragma unroll 4
    for (int i = 0; i < 64; i++) {
        int t = t0 + i;
        float4 v = xr[(size_t)t * 256 + tid];
        union { __hip_bfloat162 h; ushort2 u; } c0, c1;
        c0.h = __float22bfloat162_rn({v.x, v.y});
        c1.h = __float22bfloat162_rn({v.z, v.w});
        ushort4 uu = {c0.u.x, c0.u.y, c1.u.x, c1.u.y};
        *(ushort4*)(xb + ((size_t)(z * N_B + b) * T_S + t) * D_D + tid * 4) = uu;
        float sel = (mask_val(mk, b * T_S + t, i8) == 0) ? 1.0f : 0.0f;
        acc.x += v.x * sel; acc.y += v.y * sel;
        acc.z += v.z * sel; acc.w += v.w * sel;
    }
    float* xs = xsum + (size_t)(z * N_B + b) * D_D + tid * 4;
    atomicAdd(xs + 0, acc.x); atomicAdd(xs + 1, acc.y);
    atomicAdd(xs + 2, acc.z); atomicAdd(xs + 3, acc.w);
    if (tid < 64) {
        bool valid = (mask_val(mk, b * T_S + t0 + tid, i8) == 0);
        unsigned long long bal = __ballot(valid);
        if (tid == 0) atomicAdd(&nvalid[z * N_B + b], (int)__popcll(bal));
    }
}

// ---- k-split batched (4 rows/block) vec@W, atomicAdd into zeroed vout ----
__global__ void k_matvec(const float* __restrict__ W, const float* __restrict__ vin,
                         const float* __restrict__ bias, const int* __restrict__ bmul,
                         float scale, float* __restrict__ vout) {
    int z = blockIdx.z, bg = blockIdx.y;
    int och = blockIdx.x >> 2, kc = blockIdx.x & 3;
    int o = och * 256 + threadIdx.x;
    int brow = z * N_B + bg * 4;
    float acc[4] = {0.f, 0.f, 0.f, 0.f};
    if (kc == 0 && bias) {
        float bv = bias[o];
#pragma unroll
        for (int bb = 0; bb < 4; bb++)
            acc[bb] = bmul ? bv * (float)bmul[brow + bb] : bv;
    }
    const float* vi = vin + (size_t)brow * D_D + kc * 256;
    const float* Wp = W + (size_t)(kc * 256) * D_D + o;
#pragma unroll 4
    for (int i = 0; i < 256; i++) {
        float wv = Wp[(size_t)i * D_D];
#pragma unroll
        for (int bb = 0; bb < 4; bb++)
            acc[bb] += vi[(size_t)bb * D_D + i] * wv;
    }
#pragma unroll
    for (int bb = 0; bb < 4; bb++)
        atomicAdd(&vout[(size_t)(brow + bb) * D_D + o], acc[bb] * scale);
}

// ---- s[b,t] = x_bf16[b,t,:] . vs[b,:]  (vs has 1/SCALE folded in) ----
__global__ void k_dots(const u16* __restrict__ xb, const float* __restrict__ vs,
                       float* __restrict__ sdot) {
    int z = blockIdx.z, b = blockIdx.y;
    int t = blockIdx.x * 4 + (threadIdx.x >> 6);
    int lane = threadIdx.x & 63;
    const u16* xr = xb + ((size_t)(z * N_B + b) * T_S + t) * D_D;
    const float* vr = vs + (size_t)(z * N_B + b) * D_D;
    float acc = 0.f;
#pragma unroll
    for (int i = 0; i < 2; i++) {
        short8 v = *(const short8*)(xr + i * 512 + lane * 8);
        const float* vp = vr + i * 512 + lane * 8;
        float4 a0 = *(const float4*)(vp);
        float4 a1 = *(const float4*)(vp + 4);
        acc += bf2f((u16)v[0]) * a0.x + bf2f((u16)v[1]) * a0.y
             + bf2f((u16)v[2]) * a0.z + bf2f((u16)v[3]) * a0.w
             + bf2f((u16)v[4]) * a1.x + bf2f((u16)v[5]) * a1.y
             + bf2f((u16)v[6]) * a1.z + bf2f((u16)v[7]) * a1.w;
    }
#pragma unroll
    for (int off = 32; off; off >>= 1) acc += __shfl_xor(acc, off, 64);
    if (lane == 0) sdot[(size_t)(z * N_B + b) * T_S + t] = acc;
}

// ==== FAST GEMM with inline softmax: h = x@W1 (+b1, relu, *attn, row-reduce -> r) ====
// 128x128 tile, BK=64, bf16 16x16x32 MFMA, global_load_lds staging with XOR swizzle.
// Softmax over the (z,b) row of sdot is recomputed per block (cheap, cached).
__global__ __launch_bounds__(256, 3)
void k_gemm_bf16(const u16* __restrict__ xb, const u16* __restrict__ W1T,
                 const float* __restrict__ b1, const float* __restrict__ sdot,
                 const int* m0, const int* m1, const int* m2,
                 float* __restrict__ r) {
    int flat = blockIdx.x;
    int low3 = flat & 7, xt = (flat >> 3) & 7;
    int g = ((flat >> 6) << 3) + low3;        // 0..383
    int z = g >> 7, yt = g & 127;
    int row0 = yt * 128, N0 = xt * 128;
    int b = row0 >> 9;

    __shared__ __align__(16) u16 As[128 * 64];
    __shared__ __align__(16) u16 Bs[128 * 64];
    __shared__ float sAttn[128];
    __shared__ float redm[4], reds[4];
    int tid = threadIdx.x;
    int wave = tid >> 6, lane = tid & 63;

    // ---- inline softmax over sdot[z,b,:] with padding mask ----
    {
        const int* mk = z == 0 ? m0 : (z == 1 ? m1 : m2);
        bool i8 = mask_is_i8(mk);
        int base = (z * N_B + b) * T_S;
        float v0 = sdot[base + tid];
        float v1 = sdot[base + 256 + tid];
        if (mask_val(mk, b * T_S + tid, i8) != 0) v0 = -INFINITY;
        if (mask_val(mk, b * T_S + 256 + tid, i8) != 0) v1 = -INFINITY;
        float mx = fmaxf(v0, v1);
#pragma unroll
        for (int off = 32; off; off >>= 1) mx = fmaxf(mx, __shfl_xor(mx, off, 64));
        if (lane == 0) redm[wave] = mx;
        __syncthreads();
        mx = fmaxf(fmaxf(redm[0], redm[1]), fmaxf(redm[2], redm[3]));
        float e = __expf(v0 - mx) + __expf(v1 - mx);   // exp(-inf)=0
#pragma unroll
        for (int off = 32; off; off >>= 1) e += __shfl_xor(e, off, 64);
        if (lane == 0) reds[wave] = e;
        __syncthreads();
        float tot = reds[0] + reds[1] + reds[2] + reds[3];
        if (tid < 128) {
            int t = (row0 & 511) + tid;
            float sv = sdot[base + t];
            if (mask_val(mk, b * T_S + t, i8) != 0) sv = -INFINITY;
            sAttn[tid] = __expf(sv - mx) / tot;
        }
    }

    int wy = wave >> 1, wx = wave & 1;
    int q = lane >> 4, cidx = lane & 15;
    int srow = lane >> 3;        // row within an 8-row staging group
    int cp = lane & 7;           // LDS 16B-chunk position within row

    floatx4 acc[4][4];
#pragma unroll
    for (int mi = 0; mi < 4; mi++)
#pragma unroll
        for (int ni = 0; ni < 4; ni++)
            acc[mi][ni] = (floatx4){0.f, 0.f, 0.f, 0.f};

    const u16* abase = xb + ((size_t)z * N_B * T_S + row0) * D_D;
    const u16* bbase = W1T + (size_t)N0 * D_D;

    for (int k0 = 0; k0 < 1024; k0 += 64) {
        __syncthreads();
#pragma unroll
        for (int i = 0; i < 4; i++) {
            int r0 = wave * 32 + i * 8;
            int rr = r0 + srow;
            int gc = cp ^ (rr & 7);
            gll16(abase + (size_t)rr * D_D + k0 + gc * 8, &As[r0 * 64]);
        }
#pragma unroll
        for (int i = 0; i < 4; i++) {
            int r0 = wave * 32 + i * 8;
            int nn = r0 + srow;
            int gc = cp ^ (nn & 7);
            gll16(bbase + (size_t)nn * D_D + k0 + gc * 8, &Bs[r0 * 64]);
        }
        __syncthreads();
#pragma unroll
        for (int ks = 0; ks < 2; ks++) {
            short8 a[4], bfr[4];
#pragma unroll
            for (int mi = 0; mi < 4; mi++) {
                int m = wy * 64 + mi * 16 + cidx;
                a[mi] = *(const short8*)&As[m * 64 + (((ks << 2) | q) ^ (m & 7)) * 8];
            }
#pragma unroll
            for (int ni = 0; ni < 4; ni++) {
                int n = wx * 64 + ni * 16 + cidx;
                bfr[ni] = *(const short8*)&Bs[n * 64 + (((ks << 2) | q) ^ (n & 7)) * 8];
            }
#pragma unroll
            for (int mi = 0; mi < 4; mi++)
#pragma unroll
                for (int ni = 0; ni < 4; ni++)
                    acc[mi][ni] = __builtin_amdgcn_mfma_f32_16x16x32_bf16(
                        a[mi], bfr[ni], acc[mi][ni], 0, 0, 0);
        }
    }

    float* rrow = r + (size_t)(z * N_B + b) * D_D;
#pragma unroll
    for (int ni = 0; ni < 4; ni++) {
        int ng = N0 + wx * 64 + ni * 16 + cidx;
        float b1v = b1[ng];
        float sum = 0.f;
#pragma unroll
        for (int mi = 0; mi < 4; mi++) {
#pragma unroll
            for (int rg = 0; rg < 4; rg++) {
                int ml = wy * 64 + mi * 16 + q * 4 + rg;
                float hv = acc[mi][ni][rg] + b1v;
                hv = fmaxf(hv, 0.f);
                sum += hv * sAttn[ml];
            }
        }
        sum += __shfl_xor(sum, 16, 64);
        sum += __shfl_xor(sum, 32, 64);
        if (lane < 16) atomicAdd(&rrow[ng], sum);
    }
}

// ==== k_tail: pooled = rbuf@W2 + b2, LayerNorm, relu, classifier ====
// one block per (z,b), 512 threads
__global__ void k_tail(const float* __restrict__ rbuf, const float* __restrict__ W2,
                       const float* __restrict__ b2, const float* __restrict__ ln_g,
                       const float* __restrict__ ln_b, const float* __restrict__ Wl,
                       const float* __restrict__ bl, float* __restrict__ out) {
    int b = blockIdx.x, z = blockIdx.y;
    int tid = threadIdx.x;  // 512
    __shared__ float rrow[D_D];
    __shared__ float nr[D_D];
    __shared__ float redA[8], redB[8];
    __shared__ float ps[4][C_C];
    const float* rp = rbuf + (size_t)(z * N_B + b) * D_D;
    rrow[tid] = rp[tid];
    rrow[tid + 512] = rp[tid + 512];
    __syncthreads();
    int o0 = tid, o1 = tid + 512;
    float a0 = b2[o0], a1 = b2[o1];
#pragma unroll 8
    for (int i = 0; i < D_D; i++) {
        float rv = rrow[i];
        a0 += rv * W2[(size_t)i * D_D + o0];
        a1 += rv * W2[(size_t)i * D_D + o1];
    }
    float s1 = a0 + a1, s2 = a0 * a0 + a1 * a1;
#pragma unroll
    for (int off = 32; off; off >>= 1) {
        s1 += __shfl_xor(s1, off, 64);
        s2 += __shfl_xor(s2, off, 64);
    }
    int w = tid >> 6;
    if ((tid & 63) == 0) { redA[w] = s1; redB[w] = s2; }
    __syncthreads();
    float t1 = 0.f, t2 = 0.f;
#pragma unroll
    for (int k = 0; k < 8; k++) { t1 += redA[k]; t2 += redB[k]; }
    float mu = t1 * (1.0f / D_D);
    float var = t2 * (1.0f / D_D) - mu * mu;
    float rstd = 1.0f / sqrtf(var + 1e-12f);
    nr[o0] = fmaxf((a0 - mu) * rstd * ln_g[o0] + ln_b[o0], 0.f);
    nr[o1] = fmaxf((a1 - mu) * rstd * ln_g[o1] + ln_b[o1], 0.f);
    __syncthreads();
    if (tid < 4 * C_C) {
        int seg = tid / C_C, c = tid - seg * C_C;
        const float* wp = Wl + (size_t)(seg * 256) * C_C + c;
        const float* np = nr + seg * 256;
        float acc = 0.f;
#pragma unroll 8
        for (int d = 0; d < 256; d++)
            acc += np[d] * wp[(size_t)d * C_C];
        ps[seg][c] = acc;
    }
    __syncthreads();
    if (tid < C_C)
        out[(size_t)(z * N_B + b) * C_C + tid] =
            bl[tid] + ps[0][tid] + ps[1][tid] + ps[2][tid] + ps[3][tid];
}

extern "C" void kernel_launch(void* const* d_in, const int* in_sizes, int n_in,
                              void* d_out, int out_size, void* d_ws, size_t ws_size,
                              hipStream_t stream) {
    const float* x0 = (const float*)d_in[0];
    const float* x1 = (const float*)d_in[1];
    const float* x2 = (const float*)d_in[2];
    const int* m0 = (const int*)d_in[3];
    const int* m1 = (const int*)d_in[4];
    const int* m2 = (const int*)d_in[5];
    const float* W_attn = (const float*)d_in[6];
    const float* b_attn = (const float*)d_in[7];
    const float* W1 = (const float*)d_in[8];
    const float* b1 = (const float*)d_in[9];
    const float* W2 = (const float*)d_in[10];
    const float* b2 = (const float*)d_in[11];
    const float* ln_g = (const float*)d_in[12];
    const float* ln_b = (const float*)d_in[13];
    const float* W_last = (const float*)d_in[14];
    const float* b_last = (const float*)d_in[15];
    float* out = (float*)d_out;

    char* wsb = (char*)d_ws;
    const size_t MB = 1 << 20;
    float* WT     = (float*)(wsb);                    // 4 MB
    u16*   W1T    = (u16*)  (wsb + 4 * MB);           // 2 MB
    // zeroed region: 6MB..8MB
    float* xsum   = (float*)(wsb + 6 * MB);           // 384 KB
    float* rbuf   = (float*)(wsb + 6 * MB + 393216);  // 384 KB
    float* wsum   = (float*)(wsb + 6 * MB + 786432);  // 384 KB
    float* vs     = (float*)(wsb + 6 * MB + 1179648); // 384 KB
    int*   nvalid = (int*)  (wsb + 6 * MB + 1572864); // 384 B
    // non-zeroed
    float* sdot   = (float*)(wsb + 8 * MB);           // 192 KB
    u16*   x_bf16 = (u16*)  (wsb + 9 * MB);           // 96 MB

    hipMemsetAsync(wsb + 6 * MB, 0, 2 * MB, stream);

    k_prep  <<<1792, 256, 0, stream>>>(W_attn, W1, x0, x1, x2, m0, m1, m2,
                                       WT, W1T, xsum, nvalid, x_bf16);
    // wsum = xsum@W_attn + nvalid*b_attn
    k_matvec<<<dim3(16, 8, 3), 256, 0, stream>>>(W_attn, xsum, b_attn, nvalid, 1.0f, wsum);
    // vs = (W_attn . wsum)/SCALE  via transposed weights
    k_matvec<<<dim3(16, 8, 3), 256, 0, stream>>>(WT, wsum, nullptr, nullptr, 1.0f / SCALE, vs);
    k_dots  <<<dim3(128, 32, 3), 256, 0, stream>>>(x_bf16, vs, sdot);
    k_gemm_bf16<<<3072, 256, 0, stream>>>(x_bf16, W1T, b1, sdot, m0, m1, m2, rbuf);
    k_tail  <<<dim3(32, 3), 512, 0, stream>>>(rbuf, W2, b2, ln_g, ln_b, W_last, b_last, out);
}

// Round 4
// 404.860 us; speedup vs baseline: 1.2911x; 1.2911x over previous
//
#include <hip/hip_runtime.h>
#include <hip/hip_bf16.h>
#include <math.h>

#define N_B 32
#define T_S 512
#define D_D 1024
#define C_C 120
#define ZB 96           // 3 streams x 32 batch rows
#define SCALE 64.0f     // 2*sqrt(1024)

typedef unsigned short u16;
typedef __attribute__((ext_vector_type(8))) short short8;
typedef __attribute__((ext_vector_type(8))) unsigned short ushort8;
typedef __attribute__((ext_vector_type(4))) float floatx4;

__device__ inline u16 f2bf(float f) {
    union { __hip_bfloat16 h; u16 u; } c; c.h = __float2bfloat16(f); return c.u;
}
__device__ inline float bf2f(u16 u) {
    union { unsigned i; float f; } c; c.i = ((unsigned)u) << 16; return c.f;
}

// async global->LDS, 16B per lane. LDS dest = wave-uniform base + lane*16.
__device__ inline void gll16(const void* g, void* l) {
    __builtin_amdgcn_global_load_lds((const __attribute__((address_space(1))) void*)g,
                                     (__attribute__((address_space(3))) void*)l,
                                     16, 0, 0);
}

// ---- mask dtype robustness: harness may deliver bool as int32 or int8 ----
__device__ inline bool mask_is_i8(const int* mk) {
    bool i8 = false;
#pragma unroll
    for (int i = 0; i < 16; i++) {
        unsigned v = ((const unsigned*)mk)[i];
        if (v > 1u) i8 = true;
    }
    return i8;
}
__device__ inline int mask_val(const int* mk, int idx, bool i8) {
    return i8 ? (int)((const signed char*)mk)[idx] : mk[idx];
}

// ==== k_scan: per-(z,b) valid count + per-chunk packed base + zero pad rows ====
// grid 96 blocks x 256 threads. chunk = 64 t's; 8 chunks per row.
__global__ void k_scan(const int* m0, const int* m1, const int* m2,
                       int* __restrict__ chunk_base, int* __restrict__ cnts,
                       u16* __restrict__ xp) {
    int zb = blockIdx.x;
    int z = zb >> 5, b = zb & 31;
    const int* mk = z == 0 ? m0 : (z == 1 ? m1 : m2);
    bool i8 = mask_is_i8(mk);
    int tid = threadIdx.x;
    __shared__ int wcnt[8];
    bool v0 = (mask_val(mk, b * T_S + tid, i8) == 0);
    bool v1 = (mask_val(mk, b * T_S + 256 + tid, i8) == 0);
    unsigned long long b0 = __ballot(v0);   // wave w covers chunk w
    unsigned long long b1 = __ballot(v1);   // wave w covers chunk w+4
    int wave = tid >> 6;
    if ((tid & 63) == 0) {
        wcnt[wave] = (int)__popcll(b0);
        wcnt[wave + 4] = (int)__popcll(b1);
    }
    __syncthreads();
    __shared__ int s_cnt;
    if (tid == 0) {
        int run = 0;
#pragma unroll
        for (int c = 0; c < 8; c++) {
            chunk_base[zb * 8 + c] = run;
            run += wcnt[c];
        }
        cnts[zb] = run;
        s_cnt = run;
    }
    __syncthreads();
    int cnt = s_cnt;
    int cend = (cnt + 127) & ~127;
    if (cend > T_S) cend = T_S;
    // zero pad rows [cnt, cend)
    u16* base = xp + ((size_t)zb * T_S + cnt) * D_D;
    int n8 = (cend - cnt) * (D_D / 8);
    ushort8 zz = {0,0,0,0,0,0,0,0};
    for (int i = tid; i < n8; i += 256)
        *(ushort8*)(base + (size_t)i * 8) = zz;
}

// ==== k_prep: W_attn transpose (fp32) + W1 transpose (bf16) +
//      pack valid x rows as bf16 + masked column-sum of x ====
// blocks [0,1024): transposes; blocks [1024,1792): pack/xsum (8 chunks x 96 zb)
__global__ void k_prep(const float* __restrict__ W_attn, const float* __restrict__ W1,
                       const float* x0, const float* x1, const float* x2,
                       const int* m0, const int* m1, const int* m2,
                       const int* __restrict__ chunk_base,
                       float* __restrict__ WT, u16* __restrict__ W1T,
                       float* __restrict__ xsum, u16* __restrict__ xp) {
    int bx = blockIdx.x;
    int tid = threadIdx.x;
    if (bx < 1024) {
        int tbx = bx & 31, tby = bx >> 5;
        __shared__ float tile[32][33];
        int tx = tid & 31, ty = tid >> 5;  // ty 0..7
#pragma unroll
        for (int j = 0; j < 32; j += 8)
            tile[ty + j][tx] = W_attn[(size_t)(tby*32 + ty + j)*D_D + tbx*32 + tx];
        __syncthreads();
#pragma unroll
        for (int j = 0; j < 32; j += 8)
            WT[(size_t)(tbx*32 + ty + j)*D_D + tby*32 + tx] = tile[tx][ty + j];
        __syncthreads();
#pragma unroll
        for (int j = 0; j < 32; j += 8)
            tile[ty + j][tx] = W1[(size_t)(tby*32 + ty + j)*D_D + tbx*32 + tx];
        __syncthreads();
#pragma unroll
        for (int j = 0; j < 32; j += 8)
            W1T[(size_t)(tbx*32 + ty + j)*D_D + tby*32 + tx] = f2bf(tile[tx][ty + j]);
        return;
    }
    int idx = bx - 1024;
    int chunk = idx & 7, zb = idx >> 3;
    int z = zb >> 5, b = zb & 31;
    const float* x = z == 0 ? x0 : (z == 1 ? x1 : x2);
    const int* mk = z == 0 ? m0 : (z == 1 ? m1 : m2);
    bool i8 = mask_is_i8(mk);
    int t0 = chunk * 64;
    int slot = chunk_base[zb * 8 + chunk];
    const float4* xr = (const float4*)(x + (size_t)(b * T_S) * D_D);
    u16* pack = xp + (size_t)zb * T_S * D_D;
    float4 acc = {0.f, 0.f, 0.f, 0.f};
    for (int i = 0; i < 64; i++) {
        int t = t0 + i;
        if (mask_val(mk, b * T_S + t, i8) == 0) {   // uniform branch
            float4 v = xr[(size_t)t * 256 + tid];
            union { __hip_bfloat162 h; ushort2 u; } c0, c1;
            c0.h = __float22bfloat162_rn({v.x, v.y});
            c1.h = __float22bfloat162_rn({v.z, v.w});
            ushort4 uu = {c0.u.x, c0.u.y, c1.u.x, c1.u.y};
            *(ushort4*)(pack + (size_t)slot * D_D + tid * 4) = uu;
            slot++;
            acc.x += v.x; acc.y += v.y; acc.z += v.z; acc.w += v.w;
        }
    }
    float* xs = xsum + (size_t)zb * D_D + tid * 4;
    atomicAdd(xs + 0, acc.x); atomicAdd(xs + 1, acc.y);
    atomicAdd(xs + 2, acc.z); atomicAdd(xs + 3, acc.w);
}

// ---- 8-way k-split batched (4 rows/block) vec@W, atomicAdd into zeroed vout ----
__global__ void k_matvec(const float* __restrict__ W, const float* __restrict__ vin,
                         const float* __restrict__ bias, const int* __restrict__ bmul,
                         float scale, float* __restrict__ vout) {
    int z = blockIdx.z, bg = blockIdx.y;
    int och = blockIdx.x >> 3, kc = blockIdx.x & 7;
    int o = och * 256 + threadIdx.x;
    int brow = z * N_B + bg * 4;
    float acc[4] = {0.f, 0.f, 0.f, 0.f};
    if (kc == 0 && bias) {
        float bv = bias[o];
#pragma unroll
        for (int bb = 0; bb < 4; bb++)
            acc[bb] = bmul ? bv * (float)bmul[brow + bb] : bv;
    }
    const float* vi = vin + (size_t)brow * D_D + kc * 128;
    const float* Wp = W + (size_t)(kc * 128) * D_D + o;
#pragma unroll 4
    for (int i = 0; i < 128; i++) {
        float wv = Wp[(size_t)i * D_D];
#pragma unroll
        for (int bb = 0; bb < 4; bb++)
            acc[bb] += vi[(size_t)bb * D_D + i] * wv;
    }
#pragma unroll
    for (int bb = 0; bb < 4; bb++)
        atomicAdd(&vout[(size_t)(brow + bb) * D_D + o], acc[bb] * scale);
}

// ---- sdot[zb,i] = x_packed[zb,i,:] . vs[zb,:]  over packed valid rows ----
__global__ void k_dots(const u16* __restrict__ xp, const float* __restrict__ vs,
                       const int* __restrict__ cnts, float* __restrict__ sdot) {
    int zb = blockIdx.y;
    int t0 = blockIdx.x * 4;
    if (t0 >= cnts[zb]) return;
    int t = t0 + (threadIdx.x >> 6);
    int lane = threadIdx.x & 63;
    const u16* xr = xp + ((size_t)zb * T_S + t) * D_D;
    const float* vr = vs + (size_t)zb * D_D;
    float acc = 0.f;
#pragma unroll
    for (int i = 0; i < 2; i++) {
        short8 v = *(const short8*)(xr + i * 512 + lane * 8);
        const float* vp = vr + i * 512 + lane * 8;
        float4 a0 = *(const float4*)(vp);
        float4 a1 = *(const float4*)(vp + 4);
        acc += bf2f((u16)v[0]) * a0.x + bf2f((u16)v[1]) * a0.y
             + bf2f((u16)v[2]) * a0.z + bf2f((u16)v[3]) * a0.w
             + bf2f((u16)v[4]) * a1.x + bf2f((u16)v[5]) * a1.y
             + bf2f((u16)v[6]) * a1.z + bf2f((u16)v[7]) * a1.w;
    }
#pragma unroll
    for (int off = 32; off; off >>= 1) acc += __shfl_xor(acc, off, 64);
    if (lane == 0) sdot[(size_t)zb * T_S + t] = acc;
}

// ==== FAST GEMM on packed rows, inline softmax over i<cnt ====
// 128x128 tile, BK=64, bf16 16x16x32 MFMA, global_load_lds + XOR swizzle.
__global__ __launch_bounds__(256, 4)
void k_gemm_bf16(const u16* __restrict__ xp, const u16* __restrict__ W1T,
                 const float* __restrict__ b1, const float* __restrict__ sdot,
                 const int* __restrict__ cnts, float* __restrict__ r) {
    int flat = blockIdx.x;
    int low3 = flat & 7, xt = (flat >> 3) & 7;
    int g = ((flat >> 6) << 3) + low3;        // 0..383
    int tile = g & 3, zb = g >> 2;
    int row0 = tile * 128, N0 = xt * 128;
    int cnt = cnts[zb];
    if (row0 >= cnt) return;                  // dead tile (pad region)

    __shared__ __align__(16) u16 As[128 * 64];
    __shared__ __align__(16) u16 Bs[128 * 64];
    __shared__ float sAttn[128];
    __shared__ float redm[4], reds[4];
    int tid = threadIdx.x;
    int wave = tid >> 6, lane = tid & 63;

    // ---- inline softmax over packed sdot[zb, 0..cnt) ----
    {
        int base = zb * T_S;
        float v0 = (tid < cnt) ? sdot[base + tid] : -INFINITY;
        float v1 = (tid + 256 < cnt) ? sdot[base + 256 + tid] : -INFINITY;
        float mx = fmaxf(v0, v1);
#pragma unroll
        for (int off = 32; off; off >>= 1) mx = fmaxf(mx, __shfl_xor(mx, off, 64));
        if (lane == 0) redm[wave] = mx;
        __syncthreads();
        mx = fmaxf(fmaxf(redm[0], redm[1]), fmaxf(redm[2], redm[3]));
        float e = __expf(v0 - mx) + __expf(v1 - mx);   // exp(-inf)=0
#pragma unroll
        for (int off = 32; off; off >>= 1) e += __shfl_xor(e, off, 64);
        if (lane == 0) reds[wave] = e;
        __syncthreads();
        float tot = reds[0] + reds[1] + reds[2] + reds[3];
        if (tid < 128) {
            int t = row0 + tid;
            float av = 0.f;
            if (t < cnt) av = __expf(sdot[base + t] - mx) / tot;
            sAttn[tid] = av;
        }
    }

    int wy = wave >> 1, wx = wave & 1;
    int q = lane >> 4, cidx = lane & 15;
    int srow = lane >> 3;        // row within an 8-row staging group
    int cp = lane & 7;           // LDS 16B-chunk position within row

    floatx4 acc[4][4];
#pragma unroll
    for (int mi = 0; mi < 4; mi++)
#pragma unroll
        for (int ni = 0; ni < 4; ni++)
            acc[mi][ni] = (floatx4){0.f, 0.f, 0.f, 0.f};

    const u16* abase = xp + ((size_t)zb * T_S + row0) * D_D;
    const u16* bbase = W1T + (size_t)N0 * D_D;

    for (int k0 = 0; k0 < 1024; k0 += 64) {
        __syncthreads();
#pragma unroll
        for (int i = 0; i < 4; i++) {
            int r0 = wave * 32 + i * 8;
            int rr = r0 + srow;
            int gc = cp ^ (rr & 7);
            gll16(abase + (size_t)rr * D_D + k0 + gc * 8, &As[r0 * 64]);
        }
#pragma unroll
        for (int i = 0; i < 4; i++) {
            int r0 = wave * 32 + i * 8;
            int nn = r0 + srow;
            int gc = cp ^ (nn & 7);
            gll16(bbase + (size_t)nn * D_D + k0 + gc * 8, &Bs[r0 * 64]);
        }
        __syncthreads();
#pragma unroll
        for (int ks = 0; ks < 2; ks++) {
            short8 a[4], bfr[4];
#pragma unroll
            for (int mi = 0; mi < 4; mi++) {
                int m = wy * 64 + mi * 16 + cidx;
                a[mi] = *(const short8*)&As[m * 64 + (((ks << 2) | q) ^ (m & 7)) * 8];
            }
#pragma unroll
            for (int ni = 0; ni < 4; ni++) {
                int n = wx * 64 + ni * 16 + cidx;
                bfr[ni] = *(const short8*)&Bs[n * 64 + (((ks << 2) | q) ^ (n & 7)) * 8];
            }
#pragma unroll
            for (int mi = 0; mi < 4; mi++)
#pragma unroll
                for (int ni = 0; ni < 4; ni++)
                    acc[mi][ni] = __builtin_amdgcn_mfma_f32_16x16x32_bf16(
                        a[mi], bfr[ni], acc[mi][ni], 0, 0, 0);
        }
    }

    float* rrow = r + (size_t)zb * D_D;
#pragma unroll
    for (int ni = 0; ni < 4; ni++) {
        int ng = N0 + wx * 64 + ni * 16 + cidx;
        float b1v = b1[ng];
        float sum = 0.f;
#pragma unroll
        for (int mi = 0; mi < 4; mi++) {
#pragma unroll
            for (int rg = 0; rg < 4; rg++) {
                int ml = wy * 64 + mi * 16 + q * 4 + rg;
                float hv = acc[mi][ni][rg] + b1v;
                hv = fmaxf(hv, 0.f);
                sum += hv * sAttn[ml];
            }
        }
        sum += __shfl_xor(sum, 16, 64);
        sum += __shfl_xor(sum, 32, 64);
        if (lane < 16) atomicAdd(&rrow[ng], sum);
    }
}

// ==== k_pool: pooled = rbuf@W2 + b2, 8-way k-split, atomicAdd ====
__global__ void k_pool(const float* __restrict__ rbuf, const float* __restrict__ W2,
                       const float* __restrict__ b2, float* __restrict__ pooled) {
    int zb = blockIdx.y;
    int och = blockIdx.x >> 3, kc = blockIdx.x & 7;
    int o = och * 256 + threadIdx.x;
    float acc = (kc == 0) ? b2[o] : 0.f;
    const float* rp = rbuf + (size_t)zb * D_D + kc * 128;
    const float* Wp = W2 + (size_t)(kc * 128) * D_D + o;
#pragma unroll 4
    for (int i = 0; i < 128; i++)
        acc += rp[i] * Wp[(size_t)i * D_D];
    atomicAdd(&pooled[(size_t)zb * D_D + o], acc);
}

// ==== k_fin: LayerNorm + relu + (1024x120) classifier, 512 threads ====
__global__ void k_fin(const float* __restrict__ pooled, const float* __restrict__ ln_g,
                      const float* __restrict__ ln_b, const float* __restrict__ Wl,
                      const float* __restrict__ bl, float* __restrict__ out) {
    int zb = blockIdx.x;
    int tid = threadIdx.x;  // 512
    __shared__ float nr[D_D];
    __shared__ float redA[8], redB[8];
    __shared__ float ps[4][C_C];
    const float* p = pooled + (size_t)zb * D_D;
    int o0 = tid, o1 = tid + 512;
    float a0 = p[o0], a1 = p[o1];
    float s1 = a0 + a1, s2 = a0 * a0 + a1 * a1;
#pragma unroll
    for (int off = 32; off; off >>= 1) {
        s1 += __shfl_xor(s1, off, 64);
        s2 += __shfl_xor(s2, off, 64);
    }
    int w = tid >> 6;
    if ((tid & 63) == 0) { redA[w] = s1; redB[w] = s2; }
    __syncthreads();
    float t1 = 0.f, t2 = 0.f;
#pragma unroll
    for (int k = 0; k < 8; k++) { t1 += redA[k]; t2 += redB[k]; }
    float mu = t1 * (1.0f / D_D);
    float var = t2 * (1.0f / D_D) - mu * mu;
    float rstd = 1.0f / sqrtf(var + 1e-12f);
    nr[o0] = fmaxf((a0 - mu) * rstd * ln_g[o0] + ln_b[o0], 0.f);
    nr[o1] = fmaxf((a1 - mu) * rstd * ln_g[o1] + ln_b[o1], 0.f);
    __syncthreads();
    if (tid < 4 * C_C) {
        int seg = tid / C_C, c = tid - seg * C_C;
        const float* wp = Wl + (size_t)(seg * 256) * C_C + c;
        const float* np = nr + seg * 256;
        float acc = 0.f;
#pragma unroll 8
        for (int d = 0; d < 256; d++)
            acc += np[d] * wp[(size_t)d * C_C];
        ps[seg][c] = acc;
    }
    __syncthreads();
    if (tid < C_C)
        out[(size_t)zb * C_C + tid] =
            bl[tid] + ps[0][tid] + ps[1][tid] + ps[2][tid] + ps[3][tid];
}

extern "C" void kernel_launch(void* const* d_in, const int* in_sizes, int n_in,
                              void* d_out, int out_size, void* d_ws, size_t ws_size,
                              hipStream_t stream) {
    const float* x0 = (const float*)d_in[0];
    const float* x1 = (const float*)d_in[1];
    const float* x2 = (const float*)d_in[2];
    const int* m0 = (const int*)d_in[3];
    const int* m1 = (const int*)d_in[4];
    const int* m2 = (const int*)d_in[5];
    const float* W_attn = (const float*)d_in[6];
    const float* b_attn = (const float*)d_in[7];
    const float* W1 = (const float*)d_in[8];
    const float* b1 = (const float*)d_in[9];
    const float* W2 = (const float*)d_in[10];
    const float* b2 = (const float*)d_in[11];
    const float* ln_g = (const float*)d_in[12];
    const float* ln_b = (const float*)d_in[13];
    const float* W_last = (const float*)d_in[14];
    const float* b_last = (const float*)d_in[15];
    float* out = (float*)d_out;

    char* wsb = (char*)d_ws;
    const size_t MB = 1 << 20;
    float* WT     = (float*)(wsb);                    // 4 MB
    u16*   W1T    = (u16*)  (wsb + 4 * MB);           // 2 MB
    // zeroed region: 6MB..8MB
    float* xsum   = (float*)(wsb + 6 * MB);           // 384 KB
    float* rbuf   = (float*)(wsb + 6 * MB + 393216);  // 384 KB
    float* wsum   = (float*)(wsb + 6 * MB + 786432);  // 384 KB
    float* vs     = (float*)(wsb + 6 * MB + 1179648); // 384 KB
    float* pooled = (float*)(wsb + 6 * MB + 1572864); // 384 KB
    // non-zeroed
    float* sdot   = (float*)(wsb + 8 * MB);           // 192 KB
    int*   cbase  = (int*)  (wsb + 8 * MB + 196608);  // 3 KB
    int*   cnts   = (int*)  (wsb + 8 * MB + 199680);  // 384 B
    u16*   xp     = (u16*)  (wsb + 9 * MB);           // 96 MB packed bf16 x

    hipMemsetAsync(wsb + 6 * MB, 0, 2 * MB, stream);

    k_scan  <<<ZB, 256, 0, stream>>>(m0, m1, m2, cbase, cnts, xp);
    k_prep  <<<1792, 256, 0, stream>>>(W_attn, W1, x0, x1, x2, m0, m1, m2,
                                       cbase, WT, W1T, xsum, xp);
    // wsum = xsum@W_attn + cnt*b_attn
    k_matvec<<<dim3(32, 8, 3), 256, 0, stream>>>(W_attn, xsum, b_attn, cnts, 1.0f, wsum);
    // vs = (W_attn . wsum)/SCALE  via transposed weights
    k_matvec<<<dim3(32, 8, 3), 256, 0, stream>>>(WT, wsum, nullptr, nullptr, 1.0f / SCALE, vs);
    k_dots  <<<dim3(128, ZB), 256, 0, stream>>>(xp, vs, cnts, sdot);
    k_gemm_bf16<<<3072, 256, 0, stream>>>(xp, W1T, b1, sdot, cnts, rbuf);
    k_pool  <<<dim3(32, ZB), 256, 0, stream>>>(rbuf, W2, b2, pooled);
    k_fin   <<<ZB, 512, 0, stream>>>(pooled, ln_g, ln_b, W_last, b_last, out);
}